// Round 1
// 1200.490 us; speedup vs baseline: 1.5101x; 1.5101x over previous
//
#include <hip/hip_runtime.h>
#include <math.h>

// Problem constants: B=2, L=2048, D=1024, H=16, DK=DV=64
static constexpr int Bc = 2;
static constexpr int Lc = 2048;
static constexpr int Dc = 1024;
static constexpr int Hc = 16;
static constexpr int DKc = 64;

typedef unsigned short u16;
typedef __attribute__((ext_vector_type(8))) short s16x8;           // 8 bf16 (4 VGPRs) MFMA frag
typedef __attribute__((ext_vector_type(4))) float f32x4;           // MFMA accumulator
typedef __attribute__((ext_vector_type(4))) unsigned short u16x4;

#define MFMA(a, b, c) __builtin_amdgcn_mfma_f32_16x16x32_bf16((a), (b), (c), 0, 0, 0)

// fp32 -> bf16, round-to-nearest-even
__device__ __forceinline__ u16 f2bf(float f) {
    unsigned int u = __float_as_uint(f);
    u += 0x7fff + ((u >> 16) & 1);
    return (u16)(u >> 16);
}

// XOR-swizzled halfword index for [row][64 bf16] LDS tiles.
// 16B unit u (0..7) within a 128B row; swizzle spreads column reads over all banks.
__device__ __forceinline__ int swz(int row, int u) {
    return (row << 6) + ((u ^ (row & 7)) << 3);
}

// ---------------- block reduction helper (for LN) ----------------------------
__device__ __forceinline__ float blockReduce(float val, float* red) {
    __syncthreads();
    #pragma unroll
    for (int o = 32; o > 0; o >>= 1) val += __shfl_down(val, o, 64);
    const int lane = threadIdx.x & 63;
    const int wid = threadIdx.x >> 6;
    if (lane == 0) red[wid] = val;
    __syncthreads();
    if (threadIdx.x == 0) {
        float r = red[0];
        #pragma unroll
        for (int i = 1; i < 4; ++i) r += red[i];
        red[0] = r;
    }
    __syncthreads();
    return red[0];
}

// ---------------- weight prep: Wt[n][k] = bf16(W[k][n]) ----------------------
__global__ __launch_bounds__(256) void k_wprep(const float* __restrict__ W,
                                               u16* __restrict__ Wt) {
    __shared__ float T[64][65];
    const int t = threadIdx.x;
    const int n0 = blockIdx.x * 64, k0 = blockIdx.y * 64;
    #pragma unroll
    for (int i = 0; i < 16; ++i) {
        int flat = t + i * 256;
        int r = flat >> 6, c = flat & 63;
        T[r][c] = W[(size_t)(k0 + r) * Dc + n0 + c];
    }
    __syncthreads();
    #pragma unroll
    for (int i = 0; i < 16; ++i) {
        int flat = t + i * 256;
        int r = flat >> 6, c = flat & 63;
        Wt[(size_t)(n0 + r) * Dc + k0 + c] = f2bf(T[c][r]);
    }
}

// ---------------- generic bf16 MFMA GEMM: 64x128 tile, K=1024 ----------------
// MODE 0: A fp32 (cvt in staging), output -> head layout bf16 (qh/kh/vh)
// MODE 1: A bf16 (ao), output -> fp32 + residual (FC)
template<int MODE>
__global__ __launch_bounds__(256) void k_gemm(const void* __restrict__ Ap,
                                              const u16* __restrict__ Bt,
                                              const float* __restrict__ RES,
                                              void* __restrict__ Yp) {
    __shared__ u16 As[64 * 64];
    __shared__ u16 Bs[128 * 64];
    const int t = threadIdx.x;
    const int lane = t & 63, wid = t >> 6;
    const int wm = wid >> 1, wn = wid & 1;  // 2x2 waves, wave tile 32x64
    const int row0 = blockIdx.x * 64, col0 = blockIdx.y * 128;
    f32x4 acc[2][4] = {};
    for (int kt = 0; kt < Dc; kt += 64) {
        if constexpr (MODE == 0) {
            const float* A = (const float*)Ap;
            #pragma unroll
            for (int i = 0; i < 2; ++i) {
                int flat = t + i * 256;
                int r = flat >> 3, u = flat & 7;
                const float4* src = (const float4*)(A + (size_t)(row0 + r) * Dc + kt + u * 8);
                float4 x = src[0], y = src[1];
                union { s16x8 v; u16 q[8]; } pk;
                pk.q[0] = f2bf(x.x); pk.q[1] = f2bf(x.y); pk.q[2] = f2bf(x.z); pk.q[3] = f2bf(x.w);
                pk.q[4] = f2bf(y.x); pk.q[5] = f2bf(y.y); pk.q[6] = f2bf(y.z); pk.q[7] = f2bf(y.w);
                *(s16x8*)&As[swz(r, u)] = pk.v;
            }
        } else {
            const u16* A = (const u16*)Ap;
            #pragma unroll
            for (int i = 0; i < 2; ++i) {
                int flat = t + i * 256;
                int r = flat >> 3, u = flat & 7;
                *(s16x8*)&As[swz(r, u)] = *(const s16x8*)(A + (size_t)(row0 + r) * Dc + kt + u * 8);
            }
        }
        #pragma unroll
        for (int i = 0; i < 4; ++i) {
            int flat = t + i * 256;
            int r = flat >> 3, u = flat & 7;
            *(s16x8*)&Bs[swz(r, u)] = *(const s16x8*)(Bt + (size_t)(col0 + r) * Dc + kt + u * 8);
        }
        __syncthreads();
        #pragma unroll
        for (int ks = 0; ks < 2; ++ks) {
            const int u = ks * 4 + (lane >> 4);
            s16x8 a[2], b[4];
            #pragma unroll
            for (int m = 0; m < 2; ++m)
                a[m] = *(const s16x8*)&As[swz(wm * 32 + m * 16 + (lane & 15), u)];
            #pragma unroll
            for (int n = 0; n < 4; ++n)
                b[n] = *(const s16x8*)&Bs[swz(wn * 64 + n * 16 + (lane & 15), u)];
            #pragma unroll
            for (int m = 0; m < 2; ++m)
                #pragma unroll
                for (int n = 0; n < 4; ++n)
                    acc[m][n] = MFMA(a[m], b[n], acc[m][n]);
        }
        __syncthreads();
    }
    #pragma unroll
    for (int m = 0; m < 2; ++m) {
        #pragma unroll
        for (int i = 0; i < 4; ++i) {
            int r = row0 + wm * 32 + m * 16 + ((lane >> 4) << 2) + i;
            #pragma unroll
            for (int n = 0; n < 4; ++n) {
                int c = col0 + wn * 64 + n * 16 + (lane & 15);
                float val = acc[m][n][i];
                if constexpr (MODE == 0) {
                    u16* Y = (u16*)Yp;
                    int bb = r >> 11, l = r & (Lc - 1);
                    int h = c >> 6, dk = c & 63;
                    Y[(((size_t)(bb * Hc + h) * Lc) + l) * DKc + dk] = f2bf(val);
                } else {
                    float* Y = (float*)Yp;
                    Y[(size_t)r * Dc + c] = val + RES[(size_t)r * Dc + c];
                }
            }
        }
    }
}

// ---------------- scores: S = (Q K^T)/8 masked, bf16 MFMA, 128x128 tile ------
__global__ __launch_bounds__(256) void k_scores(const u16* __restrict__ Qh,
                                                const u16* __restrict__ Kh,
                                                const int* __restrict__ mask,
                                                float* __restrict__ attn) {
    __shared__ u16 Qs[128 * 64];
    __shared__ u16 Ks[128 * 64];
    const int t = threadIdx.x;
    const int lane = t & 63, wid = t >> 6;
    const int wm = wid >> 1, wn = wid & 1;  // 2x2 waves, wave tile 64x64
    const int z = blockIdx.z, b = z >> 4;
    const int q0 = blockIdx.x * 128, c0 = blockIdx.y * 128;
    const u16* Qp = Qh + (size_t)z * Lc * DKc;
    const u16* Kp = Kh + (size_t)z * Lc * DKc;
    #pragma unroll
    for (int i = 0; i < 4; ++i) {
        int flat = t + i * 256;
        int r = flat >> 3, u = flat & 7;
        *(s16x8*)&Qs[swz(r, u)] = *(const s16x8*)(Qp + (size_t)(q0 + r) * DKc + u * 8);
        *(s16x8*)&Ks[swz(r, u)] = *(const s16x8*)(Kp + (size_t)(c0 + r) * DKc + u * 8);
    }
    __syncthreads();
    f32x4 acc[4][4] = {};
    #pragma unroll
    for (int ks = 0; ks < 2; ++ks) {
        const int u = ks * 4 + (lane >> 4);
        s16x8 a[4], bb[4];
        #pragma unroll
        for (int m = 0; m < 4; ++m)
            a[m] = *(const s16x8*)&Qs[swz(wm * 64 + m * 16 + (lane & 15), u)];
        #pragma unroll
        for (int n = 0; n < 4; ++n)
            bb[n] = *(const s16x8*)&Ks[swz(wn * 64 + n * 16 + (lane & 15), u)];
        #pragma unroll
        for (int m = 0; m < 4; ++m)
            #pragma unroll
            for (int n = 0; n < 4; ++n)
                acc[m][n] = MFMA(a[m], bb[n], acc[m][n]);
    }
    #pragma unroll
    for (int m = 0; m < 4; ++m) {
        #pragma unroll
        for (int i = 0; i < 4; ++i) {
            int q = q0 + wm * 64 + m * 16 + ((lane >> 4) << 2) + i;
            const int* mrow = mask + ((size_t)b * Lc + q) * Lc;
            float* arow = attn + ((size_t)z * Lc + q) * Lc;
            #pragma unroll
            for (int n = 0; n < 4; ++n) {
                int c = c0 + wn * 64 + n * 16 + (lane & 15);
                float s = acc[m][n][i] * 0.125f;
                if (mrow[c] == 0) s = -1e9f;
                arow[c] = s;
            }
        }
    }
}

// ---------------- row softmax, one wave per row of 2048, in place ------------
__global__ __launch_bounds__(256) void k_softmax(float* __restrict__ attn) {
    const int lane = threadIdx.x & 63, wid = threadIdx.x >> 6;
    float4* p = (float4*)(attn + ((size_t)blockIdx.x * 4 + wid) * Lc);
    float4 v[8];
    float m = -INFINITY;
    #pragma unroll
    for (int j = 0; j < 8; ++j) {
        v[j] = p[lane + j * 64];
        m = fmaxf(m, fmaxf(fmaxf(v[j].x, v[j].y), fmaxf(v[j].z, v[j].w)));
    }
    #pragma unroll
    for (int o = 32; o > 0; o >>= 1) m = fmaxf(m, __shfl_xor(m, o, 64));
    float s = 0.f;
    #pragma unroll
    for (int j = 0; j < 8; ++j) {
        v[j].x = __expf(v[j].x - m); v[j].y = __expf(v[j].y - m);
        v[j].z = __expf(v[j].z - m); v[j].w = __expf(v[j].w - m);
        s += v[j].x + v[j].y + v[j].z + v[j].w;
    }
    #pragma unroll
    for (int o = 32; o > 0; o >>= 1) s += __shfl_xor(s, o, 64);
    const float inv = 1.0f / s;
    #pragma unroll
    for (int j = 0; j < 8; ++j) {
        v[j].x *= inv; v[j].y *= inv; v[j].z *= inv; v[j].w *= inv;
        p[lane + j * 64] = v[j];
    }
}

// ---------------- PV: AO[b,l,h*64+dv] = P @ V, bf16 MFMA, 64x64 tile ---------
__global__ __launch_bounds__(256) void k_pv(const float* __restrict__ P,
                                            const u16* __restrict__ Vh,
                                            u16* __restrict__ AO) {
    __shared__ u16 Ps[64 * 64];
    __shared__ u16 Vt[64 * 64];   // transposed: Vt[dv][k]
    const int t = threadIdx.x;
    const int lane = t & 63, wid = t >> 6;
    const int wm = wid >> 1, wn = wid & 1;  // 2x2 waves, wave tile 32x32
    const int z = blockIdx.z, b = z >> 4, h = z & 15;
    const int l0 = blockIdx.x * 64;
    const float* Pp = P + (size_t)z * Lc * Lc;
    const u16* Vp = Vh + (size_t)z * Lc * DKc;
    f32x4 acc[2][2] = {};
    for (int kt = 0; kt < Lc; kt += 64) {
        // stage P tile (fp32 -> bf16, swizzled)
        #pragma unroll
        for (int i = 0; i < 2; ++i) {
            int flat = t + i * 256;
            int r = flat >> 3, u = flat & 7;
            const float4* src = (const float4*)(Pp + (size_t)(l0 + r) * Lc + kt + u * 8);
            float4 x = src[0], y = src[1];
            union { s16x8 v; u16 q[8]; } pk;
            pk.q[0] = f2bf(x.x); pk.q[1] = f2bf(x.y); pk.q[2] = f2bf(x.z); pk.q[3] = f2bf(x.w);
            pk.q[4] = f2bf(y.x); pk.q[5] = f2bf(y.y); pk.q[6] = f2bf(y.z); pk.q[7] = f2bf(y.w);
            *(s16x8*)&Ps[swz(r, u)] = pk.v;
        }
        // stage V tile, transposed into Vt[dv][k] (swizzled)
        #pragma unroll
        for (int i = 0; i < 4; ++i) {
            int g = t + i * 256;
            int kv = g >> 4, dv0 = (g & 15) << 2;
            u16x4 vv = *(const u16x4*)(Vp + (size_t)(kt + kv) * DKc + dv0);
            int u2 = kv >> 3, klo = kv & 7;
            #pragma unroll
            for (int e = 0; e < 4; ++e) {
                int dv = dv0 + e;
                Vt[(dv << 6) + ((u2 ^ (dv & 7)) << 3) + klo] = vv[e];
            }
        }
        __syncthreads();
        #pragma unroll
        for (int ks = 0; ks < 2; ++ks) {
            const int u = ks * 4 + (lane >> 4);
            s16x8 a[2], bb[2];
            #pragma unroll
            for (int m = 0; m < 2; ++m)
                a[m] = *(const s16x8*)&Ps[swz(wm * 32 + m * 16 + (lane & 15), u)];
            #pragma unroll
            for (int n = 0; n < 2; ++n)
                bb[n] = *(const s16x8*)&Vt[swz(wn * 32 + n * 16 + (lane & 15), u)];
            #pragma unroll
            for (int m = 0; m < 2; ++m)
                #pragma unroll
                for (int n = 0; n < 2; ++n)
                    acc[m][n] = MFMA(a[m], bb[n], acc[m][n]);
        }
        __syncthreads();
    }
    #pragma unroll
    for (int m = 0; m < 2; ++m)
        #pragma unroll
        for (int i = 0; i < 4; ++i) {
            int l = l0 + wm * 32 + m * 16 + ((lane >> 4) << 2) + i;
            #pragma unroll
            for (int n = 0; n < 2; ++n) {
                int dv = wn * 32 + n * 16 + (lane & 15);
                AO[((size_t)(b * Lc + l)) * Dc + h * DKc + dv] = f2bf(acc[m][n][i]);
            }
        }
}

// ---------------- LayerNorm over D=1024 (float4), in place -------------------
__global__ __launch_bounds__(256) void k_ln(const float* __restrict__ X,
                                            const float* __restrict__ g,
                                            const float* __restrict__ bta,
                                            float* __restrict__ Y) {
    __shared__ float red[8];
    const int row = blockIdx.x;
    const float4* x = (const float4*)(X + (size_t)row * Dc);
    const float4* g4 = (const float4*)g;
    const float4* b4 = (const float4*)bta;
    float4* y = (float4*)(Y + (size_t)row * Dc);
    const int tid = threadIdx.x;
    float4 v = x[tid];
    float s = v.x + v.y + v.z + v.w;
    float ss = v.x * v.x + v.y * v.y + v.z * v.z + v.w * v.w;
    s = blockReduce(s, red);
    ss = blockReduce(ss, red);
    const float mu = s * (1.0f / Dc);
    const float var = ss * (1.0f / Dc) - mu * mu;
    const float inv = rsqrtf(var + 1e-6f);
    float4 gv = g4[tid], bv = b4[tid], o;
    o.x = (v.x - mu) * inv * gv.x + bv.x;
    o.y = (v.y - mu) * inv * gv.y + bv.y;
    o.z = (v.z - mu) * inv * gv.z + bv.z;
    o.w = (v.w - mu) * inv * gv.w + bv.w;
    y[tid] = o;
}

extern "C" void kernel_launch(void* const* d_in, const int* in_sizes, int n_in,
                              void* d_out, int out_size, void* d_ws, size_t ws_size,
                              hipStream_t stream) {
    const float* q    = (const float*)d_in[0];
    const float* k    = (const float*)d_in[1];
    const float* v    = (const float*)d_in[2];
    const int*   mask = (const int*)d_in[3];
    const float* w_q  = (const float*)d_in[4];
    const float* w_k  = (const float*)d_in[5];
    const float* w_v  = (const float*)d_in[6];
    const float* w_fc = (const float*)d_in[7];
    const float* ln_g = (const float*)d_in[8];
    const float* ln_b = (const float*)d_in[9];

    float* out  = (float*)d_out;                       // (B,L,D)
    float* attn = out + (size_t)Bc * Lc * Dc;          // (B,H,L,L)

    // workspace (bf16): 4x weightT (2 MB each) + qh/kh/vh/ao (8 MB each) = 40 MB
    u16* ws = (u16*)d_ws;
    const size_t WSLOT = (size_t)Dc * Dc;              // 1 M elems
    const size_t HSLOT = (size_t)Bc * Hc * Lc * DKc;   // 4 M elems
    u16* wqT  = ws;
    u16* wkT  = wqT + WSLOT;
    u16* wvT  = wkT + WSLOT;
    u16* wfcT = wvT + WSLOT;
    u16* qh   = wfcT + WSLOT;
    u16* kh   = qh + HSLOT;
    u16* vh   = kh + HSLOT;
    u16* ao   = vh + HSLOT;

    dim3 blk(256);
    k_wprep<<<dim3(16, 16), blk, 0, stream>>>(w_q, wqT);
    k_wprep<<<dim3(16, 16), blk, 0, stream>>>(w_k, wkT);
    k_wprep<<<dim3(16, 16), blk, 0, stream>>>(w_v, wvT);
    k_wprep<<<dim3(16, 16), blk, 0, stream>>>(w_fc, wfcT);

    k_gemm<0><<<dim3(64, 8), blk, 0, stream>>>(q, wqT, nullptr, qh);
    k_gemm<0><<<dim3(64, 8), blk, 0, stream>>>(k, wkT, nullptr, kh);
    k_gemm<0><<<dim3(64, 8), blk, 0, stream>>>(v, wvT, nullptr, vh);

    k_scores<<<dim3(16, 16, 32), blk, 0, stream>>>(qh, kh, mask, attn);
    k_softmax<<<dim3(16384), blk, 0, stream>>>(attn);
    k_pv<<<dim3(32, 1, 32), blk, 0, stream>>>(attn, vh, ao);

    k_gemm<1><<<dim3(64, 8), blk, 0, stream>>>(ao, wfcT, q, out);
    k_ln<<<dim3(Bc * Lc), blk, 0, stream>>>(out, ln_g, ln_b, out);
}

// Round 2
// 1030.001 us; speedup vs baseline: 1.7600x; 1.1655x over previous
//
#include <hip/hip_runtime.h>
#include <math.h>

// Problem constants: B=2, L=2048, D=1024, H=16, DK=DV=64
static constexpr int Bc = 2;
static constexpr int Lc = 2048;
static constexpr int Dc = 1024;
static constexpr int Hc = 16;
static constexpr int DKc = 64;

typedef unsigned short u16;
typedef __attribute__((ext_vector_type(8))) short s16x8;           // 8 bf16 (4 VGPRs) MFMA frag
typedef __attribute__((ext_vector_type(4))) float f32x4;           // MFMA accumulator

#define MFMA(a, b, c) __builtin_amdgcn_mfma_f32_16x16x32_bf16((a), (b), (c), 0, 0, 0)

// fp32 -> bf16, round-to-nearest-even
__device__ __forceinline__ u16 f2bf(float f) {
    unsigned int u = __float_as_uint(f);
    u += 0x7fff + ((u >> 16) & 1);
    return (u16)(u >> 16);
}

// XOR-swizzled halfword index for [row][64 bf16] LDS tiles (128B rows).
__device__ __forceinline__ int swz(int row, int u) {
    return (row << 6) + ((u ^ (row & 7)) << 3);
}
// XOR-swizzled halfword index for [row][128 bf16] LDS tiles (256B rows); u in [0,16).
__device__ __forceinline__ int swz128(int row, int u) {
    return (row << 7) + ((u ^ (row & 7)) << 3);
}

// ---------------- block reduction helper (for LN) ----------------------------
__device__ __forceinline__ float blockReduce(float val, float* red) {
    __syncthreads();
    #pragma unroll
    for (int o = 32; o > 0; o >>= 1) val += __shfl_down(val, o, 64);
    const int lane = threadIdx.x & 63;
    const int wid = threadIdx.x >> 6;
    if (lane == 0) red[wid] = val;
    __syncthreads();
    if (threadIdx.x == 0) {
        float r = red[0];
        #pragma unroll
        for (int i = 1; i < 4; ++i) r += red[i];
        red[0] = r;
    }
    __syncthreads();
    return red[0];
}

// ---------------- mask bit-pack: pm word w = bits of 32 consecutive mask ints -
__global__ __launch_bounds__(256) void k_mpack(const int* __restrict__ mask,
                                               unsigned* __restrict__ pm) {
    size_t gid = (size_t)blockIdx.x * 256 + threadIdx.x;
    int v = mask[gid];
    unsigned long long b = __ballot(v != 0);
    int lane = threadIdx.x & 63;
    if ((lane & 31) == 0) pm[gid >> 5] = (unsigned)(b >> (lane & 32));
}

// ---------------- weight prep: Wt[n][k] = bf16(W[k][n]) ----------------------
__global__ __launch_bounds__(256) void k_wprep(const float* __restrict__ W,
                                               u16* __restrict__ Wt) {
    __shared__ float T[64][65];
    const int t = threadIdx.x;
    const int n0 = blockIdx.x * 64, k0 = blockIdx.y * 64;
    #pragma unroll
    for (int i = 0; i < 16; ++i) {
        int flat = t + i * 256;
        int r = flat >> 6, c = flat & 63;
        T[r][c] = W[(size_t)(k0 + r) * Dc + n0 + c];
    }
    __syncthreads();
    #pragma unroll
    for (int i = 0; i < 16; ++i) {
        int flat = t + i * 256;
        int r = flat >> 6, c = flat & 63;
        Wt[(size_t)(n0 + r) * Dc + k0 + c] = f2bf(T[c][r]);
    }
}

// ---------------- V head-transpose: Vt[z][dv][l] = Vh[z][l][dv] --------------
__global__ __launch_bounds__(256) void k_vtrans(const u16* __restrict__ Vh,
                                                u16* __restrict__ Vt) {
    __shared__ u16 T[64 * 72];
    const int t = threadIdx.x;
    const int z = blockIdx.y;
    const int c0 = blockIdx.x * 64;
    const u16* src = Vh + (size_t)z * Lc * DKc;
    #pragma unroll
    for (int i = 0; i < 2; ++i) {
        int flat = t + i * 256;
        int r = flat >> 3, u = flat & 7;
        *(s16x8*)&T[r * 72 + ((u ^ ((r >> 3) & 7)) << 3)] =
            *(const s16x8*)(src + (size_t)(c0 + r) * DKc + u * 8);
    }
    __syncthreads();
    u16* dst = Vt + (size_t)z * DKc * Lc;
    #pragma unroll
    for (int i = 0; i < 2; ++i) {
        int flat = t + i * 256;
        int dv = flat >> 3, uc = flat & 7;
        union { s16x8 v; u16 q[8]; } o;
        #pragma unroll
        for (int e = 0; e < 8; ++e) {
            int cc = uc * 8 + e;
            o.q[e] = T[cc * 72 + (((dv >> 3) ^ ((cc >> 3) & 7)) << 3) + (dv & 7)];
        }
        *(s16x8*)(dst + (size_t)dv * Lc + c0 + uc * 8) = o.v;
    }
}

// ---------------- generic bf16 MFMA GEMM: 64x128 tile, K=1024 ----------------
// MODE 0: A fp32 (cvt in staging), output -> head layout bf16 (qh/kh/vh)
// MODE 1: A bf16 (ao), output -> fp32 + residual (FC)
template<int MODE>
__global__ __launch_bounds__(256) void k_gemm(const void* __restrict__ Ap,
                                              const u16* __restrict__ Bt,
                                              const float* __restrict__ RES,
                                              void* __restrict__ Yp) {
    __shared__ u16 As[64 * 64];
    __shared__ u16 Bs[128 * 64];
    const int t = threadIdx.x;
    const int lane = t & 63, wid = t >> 6;
    const int wm = wid >> 1, wn = wid & 1;  // 2x2 waves, wave tile 32x64
    const int row0 = blockIdx.x * 64, col0 = blockIdx.y * 128;
    f32x4 acc[2][4] = {};
    for (int kt = 0; kt < Dc; kt += 64) {
        if constexpr (MODE == 0) {
            const float* A = (const float*)Ap;
            #pragma unroll
            for (int i = 0; i < 2; ++i) {
                int flat = t + i * 256;
                int r = flat >> 3, u = flat & 7;
                const float4* src = (const float4*)(A + (size_t)(row0 + r) * Dc + kt + u * 8);
                float4 x = src[0], y = src[1];
                union { s16x8 v; u16 q[8]; } pk;
                pk.q[0] = f2bf(x.x); pk.q[1] = f2bf(x.y); pk.q[2] = f2bf(x.z); pk.q[3] = f2bf(x.w);
                pk.q[4] = f2bf(y.x); pk.q[5] = f2bf(y.y); pk.q[6] = f2bf(y.z); pk.q[7] = f2bf(y.w);
                *(s16x8*)&As[swz(r, u)] = pk.v;
            }
        } else {
            const u16* A = (const u16*)Ap;
            #pragma unroll
            for (int i = 0; i < 2; ++i) {
                int flat = t + i * 256;
                int r = flat >> 3, u = flat & 7;
                *(s16x8*)&As[swz(r, u)] = *(const s16x8*)(A + (size_t)(row0 + r) * Dc + kt + u * 8);
            }
        }
        #pragma unroll
        for (int i = 0; i < 4; ++i) {
            int flat = t + i * 256;
            int r = flat >> 3, u = flat & 7;
            *(s16x8*)&Bs[swz(r, u)] = *(const s16x8*)(Bt + (size_t)(col0 + r) * Dc + kt + u * 8);
        }
        __syncthreads();
        #pragma unroll
        for (int ks = 0; ks < 2; ++ks) {
            const int u = ks * 4 + (lane >> 4);
            s16x8 a[2], b[4];
            #pragma unroll
            for (int m = 0; m < 2; ++m)
                a[m] = *(const s16x8*)&As[swz(wm * 32 + m * 16 + (lane & 15), u)];
            #pragma unroll
            for (int n = 0; n < 4; ++n)
                b[n] = *(const s16x8*)&Bs[swz(wn * 64 + n * 16 + (lane & 15), u)];
            #pragma unroll
            for (int m = 0; m < 2; ++m)
                #pragma unroll
                for (int n = 0; n < 4; ++n)
                    acc[m][n] = MFMA(a[m], b[n], acc[m][n]);
        }
        __syncthreads();
    }
    #pragma unroll
    for (int m = 0; m < 2; ++m) {
        #pragma unroll
        for (int i = 0; i < 4; ++i) {
            int r = row0 + wm * 32 + m * 16 + ((lane >> 4) << 2) + i;
            #pragma unroll
            for (int n = 0; n < 4; ++n) {
                int c = col0 + wn * 64 + n * 16 + (lane & 15);
                float val = acc[m][n][i];
                if constexpr (MODE == 0) {
                    u16* Y = (u16*)Yp;
                    int bb = r >> 11, l = r & (Lc - 1);
                    int h = c >> 6, dk = c & 63;
                    Y[(((size_t)(bb * Hc + h) * Lc) + l) * DKc + dk] = f2bf(val);
                } else {
                    float* Y = (float*)Yp;
                    Y[(size_t)r * Dc + c] = val + RES[(size_t)r * Dc + c];
                }
            }
        }
    }
}

// ---------------- fused attention: scores + softmax + PV ---------------------
// One block = (z, 64-row q-strip). 4 waves x 16 rows. Two passes over K tiles:
// pass 1 -> online (m,l); pass 2 -> recompute S, write attn, accumulate O=P*V.
__global__ __launch_bounds__(256) void k_attn(const u16* __restrict__ Qh,
                                              const u16* __restrict__ Kh,
                                              const u16* __restrict__ Vt,
                                              const unsigned* __restrict__ pm,
                                              float* __restrict__ attn,
                                              u16* __restrict__ AO) {
    __shared__ u16 Qs[64 * 64];    // [q][dk]   swz
    __shared__ u16 Ks[128 * 64];   // [c][dk]   swz
    __shared__ u16 Vs[64 * 128];   // [dv][c]   swz128
    __shared__ u16 Ps[64 * 128];   // [q][c]    swz128
    const int t = threadIdx.x;
    const int lane = t & 63, w = t >> 6;
    const int z = blockIdx.y, b = z >> 4, h = z & 15;
    const int q0 = blockIdx.x * 64;
    const u16* Qp = Qh + (size_t)z * Lc * DKc;
    const u16* Kp = Kh + (size_t)z * Lc * DKc;
    const u16* Vp = Vt + (size_t)z * DKc * Lc;

    // stage Q strip (64x64)
    #pragma unroll
    for (int i = 0; i < 2; ++i) {
        int flat = t + i * 256;
        int r = flat >> 3, u = flat & 7;
        *(s16x8*)&Qs[swz(r, u)] = *(const s16x8*)(Qp + (size_t)(q0 + r) * DKc + u * 8);
    }
    const int rq = w * 16 + ((lane >> 4) << 2);  // first of this lane's 4 rows (strip-local)
    float mrow[4], lrow[4];
    #pragma unroll
    for (int i = 0; i < 4; ++i) { mrow[i] = -1e9f; lrow[i] = 0.f; }

    // ---------------- pass 1: online m, l ----------------
    for (int ct = 0; ct < 16; ++ct) {
        __syncthreads();
        #pragma unroll
        for (int i = 0; i < 4; ++i) {
            int flat = t + i * 256;
            int r = flat >> 3, u = flat & 7;
            *(s16x8*)&Ks[swz(r, u)] = *(const s16x8*)(Kp + (size_t)(ct * 128 + r) * DKc + u * 8);
        }
        __syncthreads();
        f32x4 sf[8] = {};
        #pragma unroll
        for (int ks = 0; ks < 2; ++ks) {
            const int u = ks * 4 + (lane >> 4);
            s16x8 a = *(const s16x8*)&Qs[swz(w * 16 + (lane & 15), u)];
            #pragma unroll
            for (int n = 0; n < 8; ++n) {
                s16x8 bb = *(const s16x8*)&Ks[swz(n * 16 + (lane & 15), u)];
                sf[n] = MFMA(a, bb, sf[n]);
            }
        }
        #pragma unroll
        for (int i = 0; i < 4; ++i) {
            int q = q0 + rq + i;
            const unsigned* pmr = pm + (((size_t)b * Lc + q) << 6) + ct * 4;
            unsigned mw0 = pmr[0], mw1 = pmr[1], mw2 = pmr[2], mw3 = pmr[3];
            float vals[8];
            float rmax = -1e9f;
            #pragma unroll
            for (int n = 0; n < 8; ++n) {
                unsigned mw = (n < 2) ? mw0 : (n < 4) ? mw1 : (n < 6) ? mw2 : mw3;
                unsigned bit = (mw >> ((n & 1) * 16 + (lane & 15))) & 1u;
                float s = sf[n][i] * 0.125f;
                s = bit ? s : -1e9f;
                vals[n] = s;
                rmax = fmaxf(rmax, s);
            }
            #pragma unroll
            for (int o = 1; o < 16; o <<= 1) rmax = fmaxf(rmax, __shfl_xor(rmax, o, 64));
            float mnew = fmaxf(mrow[i], rmax);
            float corr = __expf(mrow[i] - mnew);
            float ssum = 0.f;
            #pragma unroll
            for (int n = 0; n < 8; ++n) ssum += __expf(vals[n] - mnew);
            #pragma unroll
            for (int o = 1; o < 16; o <<= 1) ssum += __shfl_xor(ssum, o, 64);
            lrow[i] = lrow[i] * corr + ssum;
            mrow[i] = mnew;
        }
    }
    float invl[4];
    #pragma unroll
    for (int i = 0; i < 4; ++i) invl[i] = 1.0f / lrow[i];

    // ---------------- pass 2: write attn, accumulate O ----------------
    f32x4 oacc[4] = {};
    for (int ct = 0; ct < 16; ++ct) {
        __syncthreads();
        #pragma unroll
        for (int i = 0; i < 4; ++i) {
            int flat = t + i * 256;
            int r = flat >> 3, u = flat & 7;
            *(s16x8*)&Ks[swz(r, u)] = *(const s16x8*)(Kp + (size_t)(ct * 128 + r) * DKc + u * 8);
        }
        #pragma unroll
        for (int i = 0; i < 4; ++i) {
            int flat = t + i * 256;
            int dv = flat >> 4, u = flat & 15;
            *(s16x8*)&Vs[swz128(dv, u)] = *(const s16x8*)(Vp + (size_t)dv * Lc + ct * 128 + u * 8);
        }
        __syncthreads();
        f32x4 sf[8] = {};
        #pragma unroll
        for (int ks = 0; ks < 2; ++ks) {
            const int u = ks * 4 + (lane >> 4);
            s16x8 a = *(const s16x8*)&Qs[swz(w * 16 + (lane & 15), u)];
            #pragma unroll
            for (int n = 0; n < 8; ++n) {
                s16x8 bb = *(const s16x8*)&Ks[swz(n * 16 + (lane & 15), u)];
                sf[n] = MFMA(a, bb, sf[n]);
            }
        }
        #pragma unroll
        for (int i = 0; i < 4; ++i) {
            int q = q0 + rq + i;
            int r = rq + i;
            const unsigned* pmr = pm + (((size_t)b * Lc + q) << 6) + ct * 4;
            unsigned mw0 = pmr[0], mw1 = pmr[1], mw2 = pmr[2], mw3 = pmr[3];
            float* arow = attn + ((size_t)z * Lc + q) * Lc + ct * 128;
            #pragma unroll
            for (int n = 0; n < 8; ++n) {
                unsigned mw = (n < 2) ? mw0 : (n < 4) ? mw1 : (n < 6) ? mw2 : mw3;
                unsigned bit = (mw >> ((n & 1) * 16 + (lane & 15))) & 1u;
                float s = sf[n][i] * 0.125f;
                s = bit ? s : -1e9f;
                float p = __expf(s - mrow[i]) * invl[i];
                int c = n * 16 + (lane & 15);
                arow[c] = p;
                Ps[(r << 7) + ((((c >> 3) ^ (r & 7)) << 3)) + (c & 7)] = f2bf(p);
            }
        }
        // PV: O += P(own 16 rows) @ V (in-wave LDS dependency; compiler waits lgkmcnt)
        #pragma unroll
        for (int ks = 0; ks < 4; ++ks) {
            const int u = ks * 4 + (lane >> 4);
            const int ar = w * 16 + (lane & 15);
            s16x8 a = *(const s16x8*)&Ps[swz128(ar, u)];
            #pragma unroll
            for (int n = 0; n < 4; ++n) {
                int dv = n * 16 + (lane & 15);
                s16x8 bb = *(const s16x8*)&Vs[swz128(dv, u)];
                oacc[n] = MFMA(a, bb, oacc[n]);
            }
        }
    }
    // write O (bf16 head-merged layout for FC)
    #pragma unroll
    for (int n = 0; n < 4; ++n)
        #pragma unroll
        for (int i = 0; i < 4; ++i) {
            int q = q0 + rq + i;
            AO[((size_t)(b * Lc + q)) * Dc + h * DKc + n * 16 + (lane & 15)] = f2bf(oacc[n][i]);
        }
}

// ---------------- LayerNorm over D=1024 (float4), in place -------------------
__global__ __launch_bounds__(256) void k_ln(const float* __restrict__ X,
                                            const float* __restrict__ g,
                                            const float* __restrict__ bta,
                                            float* __restrict__ Y) {
    __shared__ float red[8];
    const int row = blockIdx.x;
    const float4* x = (const float4*)(X + (size_t)row * Dc);
    const float4* g4 = (const float4*)g;
    const float4* b4 = (const float4*)bta;
    float4* y = (float4*)(Y + (size_t)row * Dc);
    const int tid = threadIdx.x;
    float4 v = x[tid];
    float s = v.x + v.y + v.z + v.w;
    float ss = v.x * v.x + v.y * v.y + v.z * v.z + v.w * v.w;
    s = blockReduce(s, red);
    ss = blockReduce(ss, red);
    const float mu = s * (1.0f / Dc);
    const float var = ss * (1.0f / Dc) - mu * mu;
    const float inv = rsqrtf(var + 1e-6f);
    float4 gv = g4[tid], bv = b4[tid], o;
    o.x = (v.x - mu) * inv * gv.x + bv.x;
    o.y = (v.y - mu) * inv * gv.y + bv.y;
    o.z = (v.z - mu) * inv * gv.z + bv.z;
    o.w = (v.w - mu) * inv * gv.w + bv.w;
    y[tid] = o;
}

extern "C" void kernel_launch(void* const* d_in, const int* in_sizes, int n_in,
                              void* d_out, int out_size, void* d_ws, size_t ws_size,
                              hipStream_t stream) {
    const float* q    = (const float*)d_in[0];
    const float* k    = (const float*)d_in[1];
    const float* v    = (const float*)d_in[2];
    const int*   mask = (const int*)d_in[3];
    const float* w_q  = (const float*)d_in[4];
    const float* w_k  = (const float*)d_in[5];
    const float* w_v  = (const float*)d_in[6];
    const float* w_fc = (const float*)d_in[7];
    const float* ln_g = (const float*)d_in[8];
    const float* ln_b = (const float*)d_in[9];

    float* out  = (float*)d_out;                       // (B,L,D)
    float* attn = out + (size_t)Bc * Lc * Dc;          // (B,H,L,L)

    // workspace (u16 units): 4 weightT (1M elems each) + 4 big slots (4M elems)
    // + packed mask (1 MiB). Total ~41 MiB.
    u16* ws = (u16*)d_ws;
    const size_t WSLOT = (size_t)Dc * Dc;              // 1 M elems (2 MiB)
    const size_t HSLOT = (size_t)Bc * Hc * Lc * DKc;   // 4 M elems (8 MiB)
    u16* wqT  = ws;
    u16* wkT  = wqT + WSLOT;
    u16* wvT  = wkT + WSLOT;
    u16* wfcT = wvT + WSLOT;
    u16* qh   = wfcT + WSLOT;        // S1
    u16* vt   = qh + HSLOT;          // S2
    u16* kh   = vt + HSLOT;          // S3
    u16* vh   = kh + HSLOT;          // S4 (vh early, ao later)
    u16* ao   = vh;
    unsigned* pm = (unsigned*)(vh + HSLOT);

    dim3 blk(256);
    k_mpack<<<dim3((Bc * Lc * Lc) / 256), blk, 0, stream>>>(mask, pm);
    k_wprep<<<dim3(16, 16), blk, 0, stream>>>(w_q, wqT);
    k_wprep<<<dim3(16, 16), blk, 0, stream>>>(w_k, wkT);
    k_wprep<<<dim3(16, 16), blk, 0, stream>>>(w_v, wvT);
    k_wprep<<<dim3(16, 16), blk, 0, stream>>>(w_fc, wfcT);

    k_gemm<0><<<dim3(64, 8), blk, 0, stream>>>(v, wvT, nullptr, vh);
    k_vtrans<<<dim3(32, 32), blk, 0, stream>>>(vh, vt);
    k_gemm<0><<<dim3(64, 8), blk, 0, stream>>>(q, wqT, nullptr, qh);
    k_gemm<0><<<dim3(64, 8), blk, 0, stream>>>(k, wkT, nullptr, kh);

    k_attn<<<dim3(32, 32), blk, 0, stream>>>(qh, kh, vt, pm, attn, ao);

    k_gemm<1><<<dim3(64, 8), blk, 0, stream>>>(ao, wfcT, q, out);
    k_ln<<<dim3(Bc * Lc), blk, 0, stream>>>(out, ln_g, ln_b, out);
}